// Round 5
// baseline (766.498 us; speedup 1.0000x reference)
//
#include <hip/hip_runtime.h>

typedef __bf16 bf16x8_t __attribute__((ext_vector_type(8)));
typedef float f32x4_t __attribute__((ext_vector_type(4)));
typedef float f32x2_t __attribute__((ext_vector_type(2)));

#define NSTEPS 100
#define PB0 0u          // partials double-buffer: [0,32K) and [32K,64K)
#define PB1 32768u
#define COMBF 51200u    // comb-input bf16 fragments at [51200, 63488) (post-loop only)

static __device__ __forceinline__ unsigned short f2bfu(float v) {
  union { __bf16 h; unsigned short u; } c; c.h = (__bf16)v; return c.u;  // RTNE
}
static __device__ __forceinline__ unsigned int pack2bf(float a, float b) {
  return (unsigned)f2bfu(a) | ((unsigned)f2bfu(b) << 16);
}
static __device__ __forceinline__ float asf(unsigned u) {
  union { unsigned u; float f; } c; c.u = u; return c.f;
}
static __device__ __forceinline__ unsigned asu(float f) {
  union { float f; unsigned u; } c; c.f = f; return c.u;
}
union BF8U { unsigned int u[4]; bf16x8_t v; };

static __device__ __forceinline__ bf16x8_t bfrag_f32(const float* __restrict__ p, float s) {
  BF8U r;
#pragma unroll
  for (int i = 0; i < 4; ++i) r.u[i] = pack2bf(p[2*i]*s, p[2*i+1]*s);
  return r.v;
}

static __device__ __forceinline__ void comb_store(unsigned char* ldsp, int k, int row, float v) {
  *(unsigned short*)(ldsp + COMBF +
      (unsigned)((k >> 5)*1024 + (((k >> 3) & 3)*16 + row)*16 + (k & 7)*2)) = f2bfu(v);
}

// 512 threads = 8 waves = 2 waves/SIMD -> 256-reg unified budget; state fits, no spill.
__global__ __launch_bounds__(512, 2)
void hybrid_v5(const float* __restrict__ x,
               const float* __restrict__ snn_w1, const float* __restrict__ snn_b1,
               const float* __restrict__ snn_w2, const float* __restrict__ snn_b2,
               const float* __restrict__ nn_w1,  const float* __restrict__ nn_b1,
               const float* __restrict__ nn_w2,  const float* __restrict__ nn_b2,
               const float* __restrict__ conv_w, const float* __restrict__ conv_b,
               const float* __restrict__ fc_w,   const float* __restrict__ fc_b,
               const float* __restrict__ comb_w, const float* __restrict__ comb_b,
               const unsigned short* __restrict__ fcwb, int use_bf,
               float* __restrict__ out)
{
  __shared__ __align__(16) unsigned char lds[65536];
  const int tid  = threadIdx.x;
  const int w    = tid >> 6;        // wave 0..7: K-slice [128w, 128w+128)
  const int l    = tid & 63;
  const int q    = l >> 4;
  const int m    = l & 15;
  const int row0 = blockIdx.x * 16;

  const int hi  = w >> 2;
  const int ntr = w & 3;
  const int rn  = ntr*16 + m;       // owned output col 0..63
  const int rA  = hi*4 + q;         // owned row A 0..7
  const int rB  = rA + 8;           // owned row B 8..15

  const float* xr = x + (row0 + m)*105;
  const float f0 = xr[0], f1 = xr[1], f2 = xr[2], f3 = xr[3], f4 = xr[4];
  const float b2l = snn_b2[rn];

  // resident snn_w2 B-fragments: 4 k-chunks x 4 n-tiles (64 regs, AGPR-eligible)
  bf16x8_t bfr[4][4];
#pragma unroll
  for (int ci = 0; ci < 4; ++ci)
#pragma unroll
    for (int nt = 0; nt < 4; ++nt)
      bfr[ci][nt] = bfrag_f32(snn_w2 + (nt*16 + m)*1024 + (w*4 + ci)*32 + q*8, 1.f);

  // layer-1 LIF state as float2 pairs (cells 2j, 2j+1) -> packed v_pk_* math
  f32x2_t cb[16], mb[16];
  {
    const int kb = w*128 + q*8;
#pragma unroll
    for (int ci = 0; ci < 4; ++ci) {
      const float* wp = snn_w1 + (kb + ci*32)*5;
      float wa[40];
#pragma unroll
      for (int u2 = 0; u2 < 10; ++u2) {
        const float4 t4 = *(const float4*)(wp + u2*4);
        wa[u2*4+0] = t4.x; wa[u2*4+1] = t4.y; wa[u2*4+2] = t4.z; wa[u2*4+3] = t4.w;
      }
      float cc[8];
#pragma unroll
      for (int j = 0; j < 8; ++j)
        cc[j] = f0*wa[j*5] + f1*wa[j*5+1] + f2*wa[j*5+2] + f3*wa[j*5+3] + f4*wa[j*5+4]
              + snn_b1[kb + ci*32 + j];
#pragma unroll
      for (int jj = 0; jj < 4; ++jj) {
        cb[ci*4+jj].x = cc[2*jj];   cb[ci*4+jj].y = cc[2*jj+1];
        mb[ci*4+jj].x = 0.f;        mb[ci*4+jj].y = 0.f;
      }
    }
  }

  BF8U afr[4];
#pragma unroll
  for (int ci = 0; ci < 4; ++ci)
#pragma unroll
    for (int jj = 0; jj < 4; ++jj) afr[ci].u[jj] = 0u;   // spikes(t=-1) = 0

  // one LIF step: sp recovered from afr bits (exact: bf16 1.0 <-> f32 1.0),
  // mem = (0.95*mem + c) - sp in exact np op order (contract off),
  // new spikes packed via v_perm (bf16 = high16 of 1.0f/0.0f).
  auto lif_step = [&]() {
#pragma clang fp contract(off)
#pragma unroll
    for (int ci = 0; ci < 4; ++ci) {
#pragma unroll
      for (int jj = 0; jj < 4; ++jj) {
        const int idx = ci*4 + jj;
        const unsigned u = afr[ci].u[jj];
        f32x2_t sp;
        sp.x = asf(u << 16);
        sp.y = asf(u & 0xFFFF0000u);
        f32x2_t mm = mb[idx];
        mm = mm * 0.95f;          // v_pk_mul_f32 (per-component RTNE, == scalar)
        mm = mm + cb[idx];        // v_pk_add_f32
        mm = mm - sp;             // v_pk_add_f32 (neg)
        mb[idx] = mm;
        const float t0 = mm.x > 1.f ? 1.f : 0.f;
        const float t1 = mm.y > 1.f ? 1.f : 0.f;
        afr[ci].u[jj] = __builtin_amdgcn_perm(asu(t1), asu(t0), 0x07060302u);
      }
    }
  };
  lif_step();                     // spikes(t=0) in afr

  float m2A = 0.f, s2A = 0.f, cntA = 0.f;
  float m2B = 0.f, s2B = 0.f, cntB = 0.f;

  const unsigned pbase  = (unsigned)(ntr*1024 + hi*256 + m*16 + q*4);   // reduce-read base
  const unsigned wtbase = (unsigned)((w*4*64 + l)*16);                   // partial-write base
  const f32x4_t z4 = {0.f, 0.f, 0.f, 0.f};

  // one phase: reads(t-1) | MFMA(t)+writes | LIF(t+1) | reduce(t-1) | barrier
  auto phase = [&](unsigned cur, unsigned prv, bool doRead, bool doLif) {
    float vA[8], vB[8];
    if (doRead) {
#pragma unroll
      for (int s = 0; s < 8; ++s) vA[s] = *(const float*)(lds + prv + pbase + (unsigned)(s*4096));
#pragma unroll
      for (int s = 0; s < 8; ++s) vB[s] = *(const float*)(lds + prv + pbase + 512u + (unsigned)(s*4096));
    }
    f32x4_t acc[4] = {z4, z4, z4, z4};
#pragma unroll
    for (int ci = 0; ci < 4; ++ci)
#pragma unroll
      for (int nt = 0; nt < 4; ++nt)
        acc[nt] = __builtin_amdgcn_mfma_f32_16x16x32_bf16(afr[ci].v, bfr[ci][nt], acc[nt], 0,0,0);
#pragma unroll
    for (int nt = 0; nt < 4; ++nt)
      *(f32x4_t*)(lds + cur + wtbase + (unsigned)(nt*1024)) = acc[nt];
    if (doLif) lif_step();
    if (doRead) {
      float curA = (((vA[0]+vA[1]) + (vA[2]+vA[3])) + ((vA[4]+vA[5]) + (vA[6]+vA[7]))) + b2l;
      float curB = (((vB[0]+vB[1]) + (vB[2]+vB[3])) + ((vB[4]+vB[5]) + (vB[6]+vB[7]))) + b2l;
      m2A = __fsub_rn(__fadd_rn(__fmul_rn(0.95f, m2A), curA), s2A);
      s2A = m2A > 1.f ? 1.f : 0.f;  cntA += s2A;
      m2B = __fsub_rn(__fadd_rn(__fmul_rn(0.95f, m2B), curB), s2B);
      s2B = m2B > 1.f ? 1.f : 0.f;  cntB += s2B;
    }
    __syncthreads();
  };

#pragma unroll 1
  for (int tt = 0; tt < NSTEPS; tt += 2) {
    phase(PB0, PB1, tt > 0, true);                 // t = tt   (even)
    phase(PB1, PB0, true,  tt + 1 < NSTEPS - 1);   // t = tt+1 (odd)
  }
  // partials(99) sit in PB1; reduced below, folded into the NN phase.

  // ============ NN branch + final SNN reduce (reads PB1, writes PB0) ============
#pragma unroll
  for (int ci = 0; ci < 4; ++ci)
#pragma unroll
    for (int nt = 0; nt < 4; ++nt)
      bfr[ci][nt] = bfrag_f32(nn_w2 + (nt*16 + m)*1024 + (w*4 + ci)*32 + q*8, 1.f);
  {
    // final SNN reduce (t = 99)
    float vA[8], vB[8];
#pragma unroll
    for (int s = 0; s < 8; ++s) vA[s] = *(const float*)(lds + PB1 + pbase + (unsigned)(s*4096));
#pragma unroll
    for (int s = 0; s < 8; ++s) vB[s] = *(const float*)(lds + PB1 + pbase + 512u + (unsigned)(s*4096));
    float curA = (((vA[0]+vA[1]) + (vA[2]+vA[3])) + ((vA[4]+vA[5]) + (vA[6]+vA[7]))) + b2l;
    float curB = (((vB[0]+vB[1]) + (vB[2]+vB[3])) + ((vB[4]+vB[5]) + (vB[6]+vB[7]))) + b2l;
    m2A = __fsub_rn(__fadd_rn(__fmul_rn(0.95f, m2A), curA), s2A);
    s2A = m2A > 1.f ? 1.f : 0.f;  cntA += s2A;
    m2B = __fsub_rn(__fadd_rn(__fmul_rn(0.95f, m2B), curB), s2B);
    s2B = m2B > 1.f ? 1.f : 0.f;  cntB += s2B;

    // NN hidden + MFMA
    BF8U hfr[4];
    const int kb = w*128 + q*8;
#pragma unroll
    for (int ci = 0; ci < 4; ++ci) {
      const float* wp = nn_w1 + (kb + ci*32)*5;
      float wa[40];
#pragma unroll
      for (int u2 = 0; u2 < 10; ++u2) {
        const float4 t4 = *(const float4*)(wp + u2*4);
        wa[u2*4+0] = t4.x; wa[u2*4+1] = t4.y; wa[u2*4+2] = t4.z; wa[u2*4+3] = t4.w;
      }
      float hv[8];
#pragma unroll
      for (int j = 0; j < 8; ++j) {
        const float h = f0*wa[j*5] + f1*wa[j*5+1] + f2*wa[j*5+2] + f3*wa[j*5+3] + f4*wa[j*5+4]
                      + nn_b1[kb + ci*32 + j];
        hv[j] = fmaxf(h, 0.f);
      }
#pragma unroll
      for (int jj = 0; jj < 4; ++jj) hfr[ci].u[jj] = pack2bf(hv[2*jj], hv[2*jj+1]);
    }
    f32x4_t acc[4] = {z4, z4, z4, z4};
#pragma unroll
    for (int ci = 0; ci < 4; ++ci)
#pragma unroll
      for (int nt = 0; nt < 4; ++nt)
        acc[nt] = __builtin_amdgcn_mfma_f32_16x16x32_bf16(hfr[ci].v, bfr[ci][nt], acc[nt], 0,0,0);
#pragma unroll
    for (int nt = 0; nt < 4; ++nt)
      *(f32x4_t*)(lds + PB0 + wtbase + (unsigned)(nt*1024)) = acc[nt];
  }
  __syncthreads();
  {
    float vA[8], vB[8];
#pragma unroll
    for (int s = 0; s < 8; ++s) vA[s] = *(const float*)(lds + PB0 + pbase + (unsigned)(s*4096));
#pragma unroll
    for (int s = 0; s < 8; ++s) vB[s] = *(const float*)(lds + PB0 + pbase + 512u + (unsigned)(s*4096));
    const float nA = (((vA[0]+vA[1]) + (vA[2]+vA[3])) + ((vA[4]+vA[5]) + (vA[6]+vA[7]))) + nn_b2[rn];
    const float nB = (((vB[0]+vB[1]) + (vB[2]+vB[3])) + ((vB[4]+vB[5]) + (vB[6]+vB[7]))) + nn_b2[rn];
    comb_store(lds, rn,      rA, cntA * 0.0078125f);   // exact cnt/128
    comb_store(lds, rn,      rB, cntB * 0.0078125f);
    comb_store(lds, 64 + rn, rA, nA);
    comb_store(lds, 64 + rn, rB, nB);
  }
  __syncthreads();

  // ======= CNN conv + relu + pairwise maxpool -> pooled bf16 frags [0,51200) =======
  {
    const int ch = tid >> 4;          // 0..31  (row = m)
    const float cw0 = conv_w[ch*3+0], cw1 = conv_w[ch*3+1], cw2 = conv_w[ch*3+2];
    const float cbb = conv_b[ch];
    const float* xw = xr + 5;
    float xm1 = 0.f, x0v = xw[0];
#pragma unroll 1
    for (int p = 0; p < 50; ++p) {
      const float xp1 = xw[2*p + 1];
      const float xp2 = (p < 49) ? xw[2*p + 2] : 0.f;
      const float av = cw0*xm1 + cw1*x0v + cw2*xp1 + cbb;
      const float bv = cw0*x0v + cw1*xp1 + cw2*xp2 + cbb;
      const float pv = fmaxf(fmaxf(av, 0.f), fmaxf(bv, 0.f));
      const int k = ch*50 + p;
      *(unsigned short*)(lds + (unsigned)((k>>5)*1024 + (((k>>3)&3)*16 + m)*16 + (k&7)*2)) = f2bfu(pv);
      xm1 = xp1; x0v = xp2;
    }
  }
  __syncthreads();

  // ================= CNN fc: wave w owns n-tiles {2w, 2w+1}, full K=1600 =================
  {
    const int c0 = (w*2 + 0)*16 + m;
    const int c1 = (w*2 + 1)*16 + m;
    f32x4_t e0 = z4, o0 = z4, e1 = z4, o1 = z4;
    if (use_bf) {
#pragma unroll 2
      for (int kc = 0; kc < 50; kc += 2) {
        const bf16x8_t a0 = *(const bf16x8_t*)(lds + (unsigned)((kc*64 + l)*16));
        const bf16x8_t a1 = *(const bf16x8_t*)(lds + (unsigned)(((kc+1)*64 + l)*16));
        e0 = __builtin_amdgcn_mfma_f32_16x16x32_bf16(a0, *(const bf16x8_t*)(fcwb + c0*1600 + kc*32 + q*8), e0, 0,0,0);
        o0 = __builtin_amdgcn_mfma_f32_16x16x32_bf16(a1, *(const bf16x8_t*)(fcwb + c0*1600 + (kc+1)*32 + q*8), o0, 0,0,0);
        e1 = __builtin_amdgcn_mfma_f32_16x16x32_bf16(a0, *(const bf16x8_t*)(fcwb + c1*1600 + kc*32 + q*8), e1, 0,0,0);
        o1 = __builtin_amdgcn_mfma_f32_16x16x32_bf16(a1, *(const bf16x8_t*)(fcwb + c1*1600 + (kc+1)*32 + q*8), o1, 0,0,0);
      }
    } else {
#pragma unroll 2
      for (int kc = 0; kc < 50; kc += 2) {
        const bf16x8_t a0 = *(const bf16x8_t*)(lds + (unsigned)((kc*64 + l)*16));
        const bf16x8_t a1 = *(const bf16x8_t*)(lds + (unsigned)(((kc+1)*64 + l)*16));
        e0 = __builtin_amdgcn_mfma_f32_16x16x32_bf16(a0, bfrag_f32(fc_w + c0*1600 + kc*32 + q*8, 1.f), e0, 0,0,0);
        o0 = __builtin_amdgcn_mfma_f32_16x16x32_bf16(a1, bfrag_f32(fc_w + c0*1600 + (kc+1)*32 + q*8, 1.f), o0, 0,0,0);
        e1 = __builtin_amdgcn_mfma_f32_16x16x32_bf16(a0, bfrag_f32(fc_w + c1*1600 + kc*32 + q*8, 1.f), e1, 0,0,0);
        o1 = __builtin_amdgcn_mfma_f32_16x16x32_bf16(a1, bfrag_f32(fc_w + c1*1600 + (kc+1)*32 + q*8, 1.f), o1, 0,0,0);
      }
    }
    const float fb0 = fc_b[c0], fb1 = fc_b[c1];
#pragma unroll
    for (int r = 0; r < 4; ++r) {
      comb_store(lds, 128 + c0, q*4 + r, (e0[r] + o0[r]) + fb0);
      comb_store(lds, 128 + c1, q*4 + r, (e1[r] + o1[r]) + fb1);
    }
  }
  __syncthreads();

  // ================= comb matmul: waves 0..3, wave w owns n-tile w, full K=384 =================
  if (w < 4) {
    const int cn = w*16 + m;
    f32x4_t oe = z4, oo = z4;
#pragma unroll
    for (int kc = 0; kc < 12; kc += 2) {
      const bf16x8_t a0 = *(const bf16x8_t*)(lds + COMBF + (unsigned)((kc*64 + l)*16));
      const bf16x8_t a1 = *(const bf16x8_t*)(lds + COMBF + (unsigned)(((kc+1)*64 + l)*16));
      const float s0 = (kc    < 2) ? 1.28f : 1.f;   // undo /128 on snn counts -> /100
      const float s1 = (kc+1 < 2) ? 1.28f : 1.f;
      oe = __builtin_amdgcn_mfma_f32_16x16x32_bf16(a0, bfrag_f32(comb_w + cn*384 + kc*32 + q*8, s0), oe, 0,0,0);
      oo = __builtin_amdgcn_mfma_f32_16x16x32_bf16(a1, bfrag_f32(comb_w + cn*384 + (kc+1)*32 + q*8, s1), oo, 0,0,0);
    }
    const float cb2 = comb_b[cn];
#pragma unroll
    for (int r = 0; r < 4; ++r)
      out[(row0 + q*4 + r)*64 + cn] = (oe[r] + oo[r]) + cb2;
  }
}

// fc_w fp32 -> bf16 (runs every call; d_ws is re-poisoned by the harness)
__global__ __launch_bounds__(256)
void fcw_to_bf16(const float* __restrict__ src, unsigned short* __restrict__ dst) {
  const int i = (blockIdx.x * 256 + threadIdx.x) * 4;
  const float4 v = *(const float4*)(src + i);
  ushort4 o;
  o.x = f2bfu(v.x); o.y = f2bfu(v.y); o.z = f2bfu(v.z); o.w = f2bfu(v.w);
  *(ushort4*)(dst + i) = o;
}

extern "C" void kernel_launch(void* const* d_in, const int* in_sizes, int n_in,
                              void* d_out, int out_size, void* d_ws, size_t ws_size,
                              hipStream_t stream) {
  const float* x       = (const float*)d_in[0];
  const float* snn_w1  = (const float*)d_in[1];
  const float* snn_b1  = (const float*)d_in[2];
  const float* snn_w2  = (const float*)d_in[3];
  const float* snn_b2  = (const float*)d_in[4];
  const float* nn_w1   = (const float*)d_in[5];
  const float* nn_b1   = (const float*)d_in[6];
  const float* nn_w2   = (const float*)d_in[7];
  const float* nn_b2   = (const float*)d_in[8];
  const float* conv_w  = (const float*)d_in[9];
  const float* conv_b  = (const float*)d_in[10];
  const float* fc_w    = (const float*)d_in[11];
  const float* fc_b    = (const float*)d_in[12];
  const float* comb_w  = (const float*)d_in[13];
  const float* comb_b  = (const float*)d_in[14];
  float* outp = (float*)d_out;

  const int rows = in_sizes[0] / 105;          // 16384
  const int grid = rows / 16;                  // 1024

  const size_t fcw_elems = (size_t)in_sizes[11];          // 256*1600 = 409600
  const int use_bf = (ws_size >= fcw_elems * 2) ? 1 : 0;
  unsigned short* fcwb = (unsigned short*)d_ws;
  if (use_bf) {
    fcw_to_bf16<<<dim3((unsigned)(fcw_elems / 1024)), dim3(256), 0, stream>>>(fc_w, fcwb);
  }

  hybrid_v5<<<dim3(grid), dim3(512), 0, stream>>>(
      x, snn_w1, snn_b1, snn_w2, snn_b2,
      nn_w1, nn_b1, nn_w2, nn_b2,
      conv_w, conv_b, fc_w, fc_b, comb_w, comb_b,
      fcwb, use_bf, outp);
}